// Round 1
// baseline (4200.058 us; speedup 1.0000x reference)
//
#include <hip/hip_runtime.h>

#define TSTEPS 512
#define BATCH  64
#define DIN    256
#define DLAT   512

// ---------------- Kernel A: P[m,n] = x[m,:] . W_in[n,:] + b_h[n] ----------------
// M = TSTEPS*BATCH = 32768, K = DIN = 256, N = DLAT = 512. Writes into d_out.
#define BM 64
#define BN 64
#define BK 32

__global__ __launch_bounds__(256)
void precompute_gemm(const float* __restrict__ x,
                     const float* __restrict__ Win,
                     const float* __restrict__ bh,
                     float* __restrict__ P)
{
    __shared__ float As[BM][BK + 1];   // +1 pad: breaks 16-way bank conflict
    __shared__ float Ws[BN][BK + 1];
    const int m0  = blockIdx.y * BM;
    const int n0  = blockIdx.x * BN;
    const int tid = threadIdx.x;
    const int tx  = tid & 15;          // n-direction (x4)
    const int ty  = tid >> 4;          // m-direction (x4)
    const int lr  = tid >> 2;          // loader row 0..63
    const int lc  = (tid & 3) * 8;     // loader col 0,8,16,24

    float acc[4][4] = {};

    for (int kk = 0; kk < DIN; kk += BK) {
        const float* ax = x   + (size_t)(m0 + lr) * DIN + kk + lc;
        const float* aw = Win + (size_t)(n0 + lr) * DIN + kk + lc;
        float4 a0 = *(const float4*)(ax);
        float4 a1 = *(const float4*)(ax + 4);
        float4 w0 = *(const float4*)(aw);
        float4 w1 = *(const float4*)(aw + 4);
        As[lr][lc+0]=a0.x; As[lr][lc+1]=a0.y; As[lr][lc+2]=a0.z; As[lr][lc+3]=a0.w;
        As[lr][lc+4]=a1.x; As[lr][lc+5]=a1.y; As[lr][lc+6]=a1.z; As[lr][lc+7]=a1.w;
        Ws[lr][lc+0]=w0.x; Ws[lr][lc+1]=w0.y; Ws[lr][lc+2]=w0.z; Ws[lr][lc+3]=w0.w;
        Ws[lr][lc+4]=w1.x; Ws[lr][lc+5]=w1.y; Ws[lr][lc+6]=w1.z; Ws[lr][lc+7]=w1.w;
        __syncthreads();
        #pragma unroll
        for (int k = 0; k < BK; ++k) {
            float a[4], w[4];
            #pragma unroll
            for (int i = 0; i < 4; ++i) a[i] = As[ty*4+i][k];
            #pragma unroll
            for (int j = 0; j < 4; ++j) w[j] = Ws[tx*4+j][k];
            #pragma unroll
            for (int i = 0; i < 4; ++i)
                #pragma unroll
                for (int j = 0; j < 4; ++j)
                    acc[i][j] += a[i] * w[j];
        }
        __syncthreads();
    }

    float4 bv = *(const float4*)(bh + n0 + tx*4);
    #pragma unroll
    for (int i = 0; i < 4; ++i) {
        float4 v;
        v.x = acc[i][0] + bv.x; v.y = acc[i][1] + bv.y;
        v.z = acc[i][2] + bv.z; v.w = acc[i][3] + bv.w;
        *(float4*)(P + (size_t)(m0 + ty*4 + i) * DLAT + n0 + tx*4) = v;
    }
}

// ---------------- Transpose W_h (512x512) into d_ws: Wt[k][r] = W_h[r][k] --------
__global__ __launch_bounds__(256)
void transpose512(const float* __restrict__ in, float* __restrict__ out)
{
    __shared__ float tile[32][33];
    const int x0 = blockIdx.x * 32, y0 = blockIdx.y * 32;
    const int tx = threadIdx.x, ty = threadIdx.y;   // (32, 8)
    #pragma unroll
    for (int j = 0; j < 32; j += 8)
        tile[ty + j][tx] = in[(size_t)(y0 + ty + j) * DLAT + x0 + tx];
    __syncthreads();
    #pragma unroll
    for (int j = 0; j < 32; j += 8)
        out[(size_t)(x0 + ty + j) * DLAT + y0 + tx] = tile[tx][ty + j];
}

// ---------------- Kernel B: sequential scan, one batch row per workgroup ---------
// out pre-filled with P; each step reads P[t,b,:] then overwrites with h.
// Layout: 1024 threads = 8 k-groups x 128 row-quads. Thread (kq,g) accumulates
// over k in [kq*64, kq*64+64) for output rows 4g..4g+3. Wt loads: 64 lanes x
// 16B contiguous (fully coalesced, L2-resident stream).
__global__ __launch_bounds__(1024)
void rnn_scan_t(const float* __restrict__ Wt,   // [DLAT k][DLAT r]
                const float* __restrict__ h0,
                float* __restrict__ out)
{
    __shared__ float h[DLAT];
    __shared__ float p[8][DLAT];
    const int b   = blockIdx.x;
    const int tid = threadIdx.x;
    const int kq  = tid >> 7;          // 0..7
    const int g   = tid & 127;         // 0..127
    const int r4  = g * 4;

    if (tid < DLAT) h[tid] = h0[(size_t)b * DLAT + tid];
    __syncthreads();

    const float* wbase = Wt + (size_t)(kq * 64) * DLAT + r4;

    for (int t = 0; t < TSTEPS; ++t) {
        float4 acc = make_float4(0.f, 0.f, 0.f, 0.f);
        const float* wp = wbase;
        #pragma unroll 4
        for (int i4 = 0; i4 < 16; ++i4) {
            float4 hv = *(const float4*)&h[kq * 64 + i4 * 4];
            float4 wa = *(const float4*)(wp + 0 * DLAT);
            float4 wb = *(const float4*)(wp + 1 * DLAT);
            float4 wc = *(const float4*)(wp + 2 * DLAT);
            float4 wd = *(const float4*)(wp + 3 * DLAT);
            wp += 4 * DLAT;
            acc.x += wa.x*hv.x + wb.x*hv.y + wc.x*hv.z + wd.x*hv.w;
            acc.y += wa.y*hv.x + wb.y*hv.y + wc.y*hv.z + wd.y*hv.w;
            acc.z += wa.z*hv.x + wb.z*hv.y + wc.z*hv.z + wd.z*hv.w;
            acc.w += wa.w*hv.x + wb.w*hv.y + wc.w*hv.z + wd.w*hv.w;
        }
        *(float4*)&p[kq][r4] = acc;
        __syncthreads();
        if (tid < DLAT) {
            float* orow = out + ((size_t)t * BATCH + b) * DLAT;
            float v = orow[tid];
            #pragma unroll
            for (int q = 0; q < 8; ++q) v += p[q][tid];
            v = fmaxf(v, 0.f);
            h[tid] = v;
            orow[tid] = v;
        }
        __syncthreads();
    }
}

// ---------------- Fallback (no workspace): row-major W_h, one row per thread ----
__global__ __launch_bounds__(512)
void rnn_scan_row(const float* __restrict__ Wh,
                  const float* __restrict__ h0,
                  float* __restrict__ out)
{
    __shared__ float h[DLAT];
    const int b = blockIdx.x;
    const int r = threadIdx.x;
    h[r] = h0[(size_t)b * DLAT + r];
    __syncthreads();
    const float* wrow = Wh + (size_t)r * DLAT;
    for (int t = 0; t < TSTEPS; ++t) {
        float* orow = out + ((size_t)t * BATCH + b) * DLAT;
        float acc = orow[r];
        #pragma unroll 8
        for (int k = 0; k < DLAT; k += 4) {
            float4 w  = *(const float4*)(wrow + k);
            float4 hv = *(const float4*)&h[k];
            acc += w.x*hv.x + w.y*hv.y + w.z*hv.z + w.w*hv.w;
        }
        float v = fmaxf(acc, 0.f);
        __syncthreads();
        h[r] = v;
        orow[r] = v;
        __syncthreads();
    }
}

extern "C" void kernel_launch(void* const* d_in, const int* in_sizes, int n_in,
                              void* d_out, int out_size, void* d_ws, size_t ws_size,
                              hipStream_t stream)
{
    const float* x    = (const float*)d_in[0];
    const float* h0   = (const float*)d_in[1];
    const float* Win  = (const float*)d_in[2];
    const float* Wh   = (const float*)d_in[3];
    const float* bh   = (const float*)d_in[4];
    float* out = (float*)d_out;

    dim3 gA(DLAT / BN, (TSTEPS * BATCH) / BM);   // (8, 512)
    precompute_gemm<<<gA, 256, 0, stream>>>(x, Win, bh, out);

    if (ws_size >= (size_t)DLAT * DLAT * sizeof(float)) {
        float* Wt = (float*)d_ws;
        transpose512<<<dim3(16, 16), dim3(32, 8), 0, stream>>>(Wh, Wt);
        rnn_scan_t<<<BATCH, 1024, 0, stream>>>(Wt, h0, out);
    } else {
        rnn_scan_row<<<BATCH, 512, 0, stream>>>(Wh, h0, out);
    }
}